// Round 15
// baseline (162.311 us; speedup 1.0000x reference)
//
#include <hip/hip_runtime.h>
#include <stdint.h>

typedef short bf16x8 __attribute__((ext_vector_type(8)));
typedef unsigned short u16x8 __attribute__((ext_vector_type(8)));
typedef float f32x4 __attribute__((ext_vector_type(4)));
typedef float f32x16 __attribute__((ext_vector_type(16)));
typedef unsigned int u32x4 __attribute__((ext_vector_type(4)));

__device__ __forceinline__ unsigned short f2bf(float f) {
  unsigned int u = __builtin_bit_cast(unsigned int, f);
  u += 0x7fffu + ((u >> 16) & 1u);
  return (unsigned short)(u >> 16);
}

__device__ __forceinline__ unsigned int cvtpk(float a, float b) {
  unsigned int r;
  asm("v_cvt_pk_bf16_f32 %0, %1, %2" : "=v"(r) : "v"(a), "v"(b));
  return r;
}

__device__ __forceinline__ void gload_lds16(const void* g, void* l) {
  __builtin_amdgcn_global_load_lds(
      (const __attribute__((address_space(1))) unsigned int*)g,
      (__attribute__((address_space(3))) unsigned int*)l, 16, 0, 0);
}

// counted vmcnt wait (immediate must be a literal)
template <int N>
__device__ __forceinline__ void waitvm() {
  if constexpr (N == 0) asm volatile("s_waitcnt vmcnt(0)" ::: "memory");
  else if constexpr (N == 4) asm volatile("s_waitcnt vmcnt(4)" ::: "memory");
  else if constexpr (N == 8) asm volatile("s_waitcnt vmcnt(8)" ::: "memory");
  else static_assert(N == 0, "unsupported vmcnt literal");
}

// ---------------- fused prep: hs cvt + both weight transposes (one launch) ----------
__global__ __launch_bounds__(256) void prep_kernel(const float* __restrict__ hs,
                                                   unsigned short* __restrict__ hs_bf,
                                                   const float* __restrict__ w_attn,
                                                   unsigned short* __restrict__ wattnT,
                                                   const float* __restrict__ w_proj,
                                                   unsigned short* __restrict__ wprojT) {
  __shared__ unsigned short t[64][68];
  const int bx = blockIdx.x;
  const int tid = threadIdx.x;
  if (bx < 2048) {
    const int n8 = 8192 * 1024 / 8;
    int i = bx * 256 + tid;
    const int stride = 2048 * 256;
    for (; i < n8; i += stride) {
      float4 a = ((const float4*)hs)[2 * i];
      float4 b = ((const float4*)hs)[2 * i + 1];
      u16x8 o;
      o[0] = f2bf(a.x); o[1] = f2bf(a.y); o[2] = f2bf(a.z); o[3] = f2bf(a.w);
      o[4] = f2bf(b.x); o[5] = f2bf(b.y); o[6] = f2bf(b.z); o[7] = f2bf(b.w);
      ((u16x8*)hs_bf)[i] = o;
    }
    return;
  }
  const float* in;
  unsigned short* out;
  int R, C, c0, r0;
  if (bx < 2816) {
    int i = bx - 2048;
    in = w_attn; out = wattnT; R = 1024; C = 3072;
    c0 = (i % 48) * 64; r0 = (i / 48) * 64;
  } else {
    int i = bx - 2816;
    in = w_proj; out = wprojT; R = 1024; C = 1024;
    c0 = (i & 15) * 64; r0 = (i >> 4) * 64;
  }
#pragma unroll
  for (int i = 0; i < 4; ++i) {
    int idx = tid + i * 256;
    int rr = idx >> 4, cc4 = (idx & 15) * 4;
    float4 v = *(const float4*)(in + (size_t)(r0 + rr) * C + c0 + cc4);
    t[rr][cc4] = f2bf(v.x);
    t[rr][cc4 + 1] = f2bf(v.y);
    t[rr][cc4 + 2] = f2bf(v.z);
    t[rr][cc4 + 3] = f2bf(v.w);
  }
  __syncthreads();
#pragma unroll
  for (int i = 0; i < 2; ++i) {
    int idx = tid + i * 256;
    int row = idx >> 3, ch = (idx & 7) * 8;
    u16x8 o;
#pragma unroll
    for (int j = 0; j < 8; ++j) o[j] = t[ch + j][row];
    *(u16x8*)(out + (size_t)(c0 + row) * R + r0 + ch) = o;
  }
}

// ---------------- batched transpose bf16[z][R][C] -> bf16[z][C][R], vectorized ----------
__global__ __launch_bounds__(256) void transpose_b16(const unsigned short* __restrict__ in,
                                                     unsigned short* __restrict__ out,
                                                     int R, int C) {
  __shared__ unsigned short t[64][68];
  const unsigned short* ip = in + (size_t)blockIdx.z * R * C;
  unsigned short* op = out + (size_t)blockIdx.z * R * C;
  int c0 = blockIdx.x * 64, r0 = blockIdx.y * 64;
  int tid = threadIdx.x;
#pragma unroll
  for (int i = 0; i < 2; ++i) {
    int idx = tid + i * 256;
    int rr = idx >> 3, cc8 = (idx & 7) * 8;
    u16x8 v = *(const u16x8*)(ip + (size_t)(r0 + rr) * C + c0 + cc8);
    *(u16x8*)&t[rr][cc8] = v;
  }
  __syncthreads();
#pragma unroll
  for (int i = 0; i < 2; ++i) {
    int idx = tid + i * 256;
    int row = idx >> 3, ch = (idx & 7) * 8;
    u16x8 o;
#pragma unroll
    for (int j = 0; j < 8; ++j) o[j] = t[ch + j][row];
    *(u16x8*)(op + (size_t)(c0 + row) * R + r0 + ch) = o;
  }
}

// XCD-bijective block swizzle (requires nwg % 8 == 0)
__device__ __forceinline__ void xcd_swizzle(int gx, int gy, int& bn, int& bm) {
  int orig = blockIdx.y * gx + blockIdx.x;
  int cpx = (gx * gy) >> 3;
  int swz = (orig & 7) * cpx + (orig >> 3);
  bn = swz % gx;
  bm = swz / gx;
}

// =========== 128M x 256N window-pipelined K-loop (BK=64, 16 tiles) ===========
__device__ __forceinline__ void kloop_128x256(const unsigned short* __restrict__ Ab,
                                              const unsigned short* __restrict__ Bb,
                                              char* smem, f32x4 (*acc)[4]) {
  const int tid = threadIdx.x;
  const int lane = tid & 63, wid = tid >> 6;
  const int g = lane >> 4, r = lane & 15;
  const int wr = wid >> 2, wc = wid & 3;

  int aoff[4][2], boff[4][2];
#pragma unroll
  for (int m4 = 0; m4 < 4; ++m4)
#pragma unroll
    for (int ks = 0; ks < 2; ++ks) {
      int row = wr * 64 + m4 * 16 + r;
      aoff[m4][ks] = row * 128 + ((ks * 64 + g * 16) ^ ((row & 7) << 4));
    }
#pragma unroll
  for (int ni = 0; ni < 4; ++ni)
#pragma unroll
    for (int ks = 0; ks < 2; ++ks) {
      int row = wc * 64 + ni * 16 + r;
      boff[ni][ks] = row * 128 + ((ks * 64 + g * 16) ^ ((row & 7) << 4));
    }

  const int sc = (((tid & 7) ^ ((tid >> 3) & 7)) << 4) >> 1;
  const int srow = tid >> 3;

  auto stageA = [&](int T) {
#pragma unroll
    for (int p = 0; p < 2; ++p)
      gload_lds16(Ab + (size_t)(p * 64 + srow) * 1024 + T * 64 + sc,
                  smem + (T & 1) * 16384 + (p * 512 + tid) * 16);
  };
  auto stageB = [&](int T, int hh) {
#pragma unroll
    for (int p = 0; p < 2; ++p)
      gload_lds16(Bb + (size_t)(hh * 128 + p * 64 + srow) * 1024 + T * 64 + sc,
                  smem + 32768 + (T & 1) * 32768 + hh * 16384 + (p * 512 + tid) * 16);
  };

  // prologue: tile 0
  stageA(0); stageB(0, 0); stageB(0, 1);

#pragma unroll 1
  for (int i = 0; i < 8; ++i) {
#pragma unroll
    for (int w = 0; w < 2; ++w) {
      const int T = 2 * i + w;
      const int abase = (T & 1) * 16384;
      const int bbase = 32768 + (T & 1) * 32768;
      const int fT = T + 1;
      waitvm<0>();
      __builtin_amdgcn_s_barrier();
      bf16x8 bfr[4];
#pragma unroll
      for (int ph = 0; ph < 4; ++ph) {
        const int ks = ph >> 1, mh = ph & 1;
        if (fT < 16) {
          if (ph == 0) stageA(fT);
          else if (ph == 1) stageB(fT, 0);
          else if (ph == 2) stageB(fT, 1);
        }
        if (mh == 0) {
#pragma unroll
          for (int ni = 0; ni < 4; ++ni)
            bfr[ni] = *(const bf16x8*)(smem + bbase + boff[ni][ks]);
        }
        bf16x8 afr[2];
#pragma unroll
        for (int m = 0; m < 2; ++m)
          afr[m] = *(const bf16x8*)(smem + abase + aoff[mh * 2 + m][ks]);
        asm volatile("s_waitcnt lgkmcnt(0)" ::: "memory");
        __builtin_amdgcn_sched_barrier(0);
        __builtin_amdgcn_s_setprio(1);
#pragma unroll
        for (int m = 0; m < 2; ++m)
#pragma unroll
          for (int ni = 0; ni < 4; ++ni)
            acc[mh * 2 + m][ni] =
                __builtin_amdgcn_mfma_f32_16x16x32_bf16(afr[m], bfr[ni], acc[mh * 2 + m][ni], 0, 0, 0);
        __builtin_amdgcn_s_setprio(0);
      }
    }
  }
}

// ---------------- GEMM1: qkv = hs @ W + b, scatter to q/k/v [B,H,S,D] bf16 ----------------
__global__ __launch_bounds__(512, 2) void gemm_qkv(const unsigned short* __restrict__ A,
                                                   const unsigned short* __restrict__ Bt,
                                                   const float* __restrict__ bias,
                                                   unsigned short* __restrict__ qb,
                                                   unsigned short* __restrict__ kb,
                                                   unsigned short* __restrict__ vb) {
  __shared__ __align__(16) char smem[98304];
  const int tid = threadIdx.x;
  const int lane = tid & 63, wid = tid >> 6;
  const int g = lane >> 4, r = lane & 15;
  const int wr = wid >> 2, wc = wid & 3;
  int bn, bm;
  xcd_swizzle(12, 64, bn, bm);
  f32x4 acc[4][4] = {};
  kloop_128x256(A + (size_t)(bm * 128) * 1024, Bt + (size_t)(bn * 256) * 1024, smem, acc);

  const int colbase = bn * 256 + wc * 64;
  const int rowbase = bm * 128 + wr * 64;
  const int sec = bn >> 2;
  const float QSCALE = 0.125f * 1.44269504f;
#pragma unroll
  for (int m = 0; m < 4; ++m) {
#pragma unroll
    for (int n = 0; n < 4; ++n) {
#pragma unroll
      for (int reg = 0; reg < 4; ++reg) {
        int gm = rowbase + m * 16 + g * 4 + reg;
        int gn = colbase + n * 16 + r;
        float val = acc[m][n][reg] + bias[gn];
        int bb = gm >> 11, s = gm & 2047;
        int hc = gn & 1023;
        int h = hc >> 6, d = hc & 63;
        size_t oidx = (((size_t)(bb * 16 + h)) * 2048 + s) * 64 + d;
        if (sec == 0) qb[oidx] = f2bf(val * QSCALE);
        else if (sec == 1) kb[oidx] = f2bf(val);
        else vb[oidx] = f2bf(val);
      }
    }
  }
}

// ---------------- GEMM2: out = attn_out @ Wp + b (f32 out) ----------------
__global__ __launch_bounds__(512, 2) void gemm_proj(const unsigned short* __restrict__ A,
                                                    const unsigned short* __restrict__ Bt,
                                                    const float* __restrict__ bias,
                                                    float* __restrict__ out) {
  __shared__ __align__(16) char smem[98304];
  const int tid = threadIdx.x;
  const int lane = tid & 63, wid = tid >> 6;
  const int g = lane >> 4, r = lane & 15;
  const int wr = wid >> 2, wc = wid & 3;
  int bn, bm;
  xcd_swizzle(4, 64, bn, bm);
  f32x4 acc[4][4] = {};
  kloop_128x256(A + (size_t)(bm * 128) * 1024, Bt + (size_t)(bn * 256) * 1024, smem, acc);

  const int colbase = bn * 256 + wc * 64;
  const int rowbase = bm * 128 + wr * 64;
#pragma unroll
  for (int m = 0; m < 4; ++m) {
#pragma unroll
    for (int n = 0; n < 4; ++n) {
#pragma unroll
      for (int reg = 0; reg < 4; ++reg) {
        int gm = rowbase + m * 16 + g * 4 + reg;
        int gn = colbase + n * 16 + r;
        out[(size_t)gm * 1024 + gn] = acc[m][n][reg] + bias[gn];
      }
    }
  }
}

// ---------------- flash attention: 2-wave blocks (64 q-rows), uniform pairing ----------
// q [B,H,S,D] (pre-scaled by 0.125*log2e), k [B,H,S,D], vt [B,H,D,S] -> aout [B*S,E] bf16
// Block o (grid 1024): bh = (o&7) + 8*(o>>7) (head-per-XCD); p = (o>>3)&15; the block
// handles q-chunks {p, 31-p} of 64 rows -> exactly 33 KV-tiles per block (uniform).
// 4 blocks/CU co-resident = 4 independent tile-streams (vs 2 before).
__global__ __launch_bounds__(128) void attn_kernel(const unsigned short* __restrict__ qb,
                                                   const unsigned short* __restrict__ kb,
                                                   const unsigned short* __restrict__ vtb,
                                                   unsigned short* __restrict__ aout) {
  __shared__ char smem[32768];  // K dbuf 2x8KB @0 ; V dbuf 2x8KB @16384
  const int tid = threadIdx.x;
  const int wid = tid >> 6, lane = tid & 63;
  const int c = lane & 31, h = lane >> 5;
  const int o = blockIdx.x;
  const int p = (o >> 3) & 15;
  const int bh = (o & 7) + 8 * (o >> 7);
  const unsigned short* qbase = qb + (size_t)bh * 2048 * 64;
  const unsigned short* kbh = kb + (size_t)bh * 2048 * 64;
  const unsigned short* vbh = vtb + (size_t)bh * 64 * 2048;

  // staging geometry: wave w covers bytes [w*4KB, (w+1)*4KB) of each 8KB tile, 4 passes
  int kof[4], vof[4], dstc[4];
#pragma unroll
  for (int i = 0; i < 4; ++i) {
    int ob = (wid * 4 + i) * 1024 + lane * 16;
    int row = ob >> 7;
    int ss = ((ob >> 4) & 7) ^ (row & 7);
    kof[i] = row * 64 + ss * 8;
    vof[i] = row * 2048 + ss * 8;
    dstc[i] = (wid * 4 + i) * 1024;
  }

  // LDS fragment read offsets (tile-invariant; shared by K and V reads)
  int off0[4], off1[4];
#pragma unroll
  for (int ks = 0; ks < 4; ++ks) {
    const int sl = ((2 * ks + h) ^ (c & 7)) << 4;
    off0[ks] = c * 128 + sl;
    off1[ks] = (32 + c) * 128 + sl;
  }

  auto mkpa = [&](const f32x16& P, bf16x8& paA, bf16x8& paB) {
    unsigned c0 = cvtpk(P[0], P[1]), c2 = cvtpk(P[2], P[3]);
    unsigned c4 = cvtpk(P[4], P[5]), c6 = cvtpk(P[6], P[7]);
    unsigned c8 = cvtpk(P[8], P[9]), c10 = cvtpk(P[10], P[11]);
    unsigned c12 = cvtpk(P[12], P[13]), c14 = cvtpk(P[14], P[15]);
    auto s0 = __builtin_amdgcn_permlane32_swap(c0, c4, false, false);
    auto s1 = __builtin_amdgcn_permlane32_swap(c2, c6, false, false);
    auto s2 = __builtin_amdgcn_permlane32_swap(c8, c12, false, false);
    auto s3 = __builtin_amdgcn_permlane32_swap(c10, c14, false, false);
    u32x4 wA = {s0[0], s1[0], s0[1], s1[1]};
    u32x4 wB = {s2[0], s3[0], s2[1], s3[1]};
    paA = __builtin_bit_cast(bf16x8, wA);
    paB = __builtin_bit_cast(bf16x8, wB);
  };

#pragma unroll 1
  for (int pi = 0; pi < 2; ++pi) {
    const int chunk = (pi == 0) ? p : (31 - p);
    const int qrow0 = chunk * 64 + wid * 32;
    const int qg = qrow0 + c;  // this lane's q-row

    const unsigned short* kpt = kbh;
    const unsigned short* vpt = vbh;

    bf16x8 aq[4];
#pragma unroll
    for (int ks = 0; ks < 4; ++ks)
      aq[ks] = *(const bf16x8*)(qbase + (size_t)qg * 64 + ks * 16 + h * 8);

    f32x16 o0 = {}, o1 = {};
    float lrow = 0.f;

    const int nkv = chunk + 1;
    int cur = 0;
    // stage tile 0 into buf 0
#pragma unroll
    for (int i = 0; i < 4; ++i) {
      gload_lds16(kpt + kof[i], smem + dstc[i]);
      gload_lds16(vpt + vof[i], smem + 16384 + dstc[i]);
    }
    kpt += 4096; vpt += 64;

#pragma unroll 1
    for (int kt = 0; kt < nkv; ++kt) {
      const int kv0 = kt * 64;
      if (kt + 1 < nkv) {
        const int nb = (cur ^ 1) * 8192;
#pragma unroll
        for (int i = 0; i < 4; ++i) {
          gload_lds16(kpt + kof[i], smem + nb + dstc[i]);
          gload_lds16(vpt + vof[i], smem + 16384 + nb + dstc[i]);
        }
        kpt += 4096; vpt += 64;
        waitvm<8>();  // wait only for tile kt's 8 loads (oldest-first)
      } else {
        waitvm<0>();
      }
      __builtin_amdgcn_s_barrier();
      __builtin_amdgcn_sched_barrier(0);
      char* Kt = smem + cur * 8192;
      char* Vt = smem + 16384 + cur * 8192;

      // QK^T swapped: sw = mfma32x32(K_block, Q) -> D[kv][q], q = lane&31
      f32x16 sw0 = {}, sw1 = {};
#pragma unroll
      for (int ks = 0; ks < 4; ++ks) {
        bf16x8 k0 = *(const bf16x8*)(Kt + off0[ks]);
        bf16x8 k1 = *(const bf16x8*)(Kt + off1[ks]);
        __builtin_amdgcn_s_setprio(1);
        sw0 = __builtin_amdgcn_mfma_f32_32x32x16_bf16(k0, aq[ks], sw0, 0, 0, 0);
        sw1 = __builtin_amdgcn_mfma_f32_32x32x16_bf16(k1, aq[ks], sw1, 0, 0, 0);
        __builtin_amdgcn_s_setprio(0);
      }

      // causal mask on the last (diagonal) tile only
      if (kt == nkv - 1) {
#pragma unroll
        for (int t = 0; t < 16; ++t) {
          int crow = (t & 3) + 8 * (t >> 2) + 4 * h;
          sw0[t] = (kv0 + crow > qg) ? -1e30f : sw0[t];
          sw1[t] = (kv0 + 32 + crow > qg) ? -1e30f : sw1[t];
        }
      }

      // fixed-max: P = exp2(s) directly; row-sum tree + one shfl
      float s_[16];
#pragma unroll
      for (int t = 0; t < 16; ++t) {
        sw0[t] = __builtin_amdgcn_exp2f(sw0[t]);
        sw1[t] = __builtin_amdgcn_exp2f(sw1[t]);
        s_[t] = sw0[t] + sw1[t];
      }
#pragma unroll
      for (int s = 8; s > 0; s >>= 1)
#pragma unroll
        for (int t = 0; t < 8; ++t)
          if (t < s) s_[t] += s_[t + s];
      lrow += s_[0] + __shfl_xor(s_[0], 32);

      // P -> bf16 A-frags fully in-register
      bf16x8 pa[4];
      mkpa(sw0, pa[0], pa[1]);
      mkpa(sw1, pa[2], pa[3]);

      // PV: o += P x V
#pragma unroll
      for (int kst = 0; kst < 4; ++kst) {
        bf16x8 v0 = *(const bf16x8*)(Vt + off0[kst]);
        bf16x8 v1 = *(const bf16x8*)(Vt + off1[kst]);
        __builtin_amdgcn_s_setprio(1);
        o0 = __builtin_amdgcn_mfma_f32_32x32x16_bf16(pa[kst], v0, o0, 0, 0, 0);
        o1 = __builtin_amdgcn_mfma_f32_32x32x16_bf16(pa[kst], v1, o1, 0, 0, 0);
        __builtin_amdgcn_s_setprio(0);
      }
      __builtin_amdgcn_s_barrier();  // both waves done reading buf[cur]
      cur ^= 1;
    }

    // normalize: broadcast 1/l to row owners, write out
    const int b_ = bh >> 4, hh = bh & 15;
    float linv = 1.f / lrow;
    float invt[16];
#pragma unroll
    for (int t = 0; t < 16; ++t)
      invt[t] = __shfl(linv, (t & 3) + 8 * (t >> 2) + 4 * h);
#pragma unroll
    for (int t = 0; t < 16; ++t) {
      int rowg = b_ * 2048 + qrow0 + (t & 3) + 8 * (t >> 2) + 4 * h;
      unsigned short* rp = aout + (size_t)rowg * 1024 + hh * 64;
      rp[c] = f2bf(o0[t] * invt[t]);
      rp[32 + c] = f2bf(o1[t] * invt[t]);
    }
  }
}

extern "C" void kernel_launch(void* const* d_in, const int* in_sizes, int n_in,
                              void* d_out, int out_size, void* d_ws, size_t ws_size,
                              hipStream_t stream) {
  const float* hs = (const float*)d_in[0];      // [4,2048,1024]
  const float* w_attn = (const float*)d_in[1];  // [1024,3072]
  const float* b_attn = (const float*)d_in[2];  // [3072]
  const float* w_proj = (const float*)d_in[3];  // [1024,1024]
  const float* b_proj = (const float*)d_in[4];  // [1024]
  float* out = (float*)d_out;                   // [4,2048,1024] f32
  char* ws = (char*)d_ws;
  size_t off = 0;
  auto alloc = [&](size_t sz) {
    char* p = ws + off;
    off = (off + sz + 255) & ~(size_t)255;
    return p;
  };
  unsigned short* hs_bf = (unsigned short*)alloc((size_t)8192 * 1024 * 2);
  unsigned short* wattnT = (unsigned short*)alloc((size_t)3072 * 1024 * 2);
  unsigned short* wprojT = (unsigned short*)alloc((size_t)1024 * 1024 * 2);
  unsigned short* qbuf = (unsigned short*)alloc((size_t)8192 * 1024 * 2);
  unsigned short* kbuf = (unsigned short*)alloc((size_t)8192 * 1024 * 2);
  unsigned short* vb = (unsigned short*)alloc((size_t)8192 * 1024 * 2);
  unsigned short* vtb = (unsigned short*)alloc((size_t)8192 * 1024 * 2);
  unsigned short* aout = hs_bf;  // hs_bf dead after gemm_qkv; reuse

  prep_kernel<<<3072, 256, 0, stream>>>(hs, hs_bf, w_attn, wattnT, w_proj, wprojT);
  gemm_qkv<<<dim3(12, 64), 512, 0, stream>>>(hs_bf, wattnT, b_attn, qbuf, kbuf, vb);
  transpose_b16<<<dim3(1, 32, 64), 256, 0, stream>>>(vb, vtb, 2048, 64);
  attn_kernel<<<1024, 128, 0, stream>>>(qbuf, kbuf, vtb, aout);
  gemm_proj<<<dim3(4, 64), 512, 0, stream>>>(aout, wprojT, b_proj, out);
}

// Round 16
// 151.686 us; speedup vs baseline: 1.0700x; 1.0700x over previous
//
#include <hip/hip_runtime.h>
#include <stdint.h>

typedef short bf16x8 __attribute__((ext_vector_type(8)));
typedef unsigned short u16x8 __attribute__((ext_vector_type(8)));
typedef float f32x4 __attribute__((ext_vector_type(4)));
typedef float f32x16 __attribute__((ext_vector_type(16)));
typedef unsigned int u32x4 __attribute__((ext_vector_type(4)));

__device__ __forceinline__ unsigned short f2bf(float f) {
  unsigned int u = __builtin_bit_cast(unsigned int, f);
  u += 0x7fffu + ((u >> 16) & 1u);
  return (unsigned short)(u >> 16);
}

__device__ __forceinline__ unsigned int cvtpk(float a, float b) {
  unsigned int r;
  asm("v_cvt_pk_bf16_f32 %0, %1, %2" : "=v"(r) : "v"(a), "v"(b));
  return r;
}

__device__ __forceinline__ void gload_lds16(const void* g, void* l) {
  __builtin_amdgcn_global_load_lds(
      (const __attribute__((address_space(1))) unsigned int*)g,
      (__attribute__((address_space(3))) unsigned int*)l, 16, 0, 0);
}

// counted vmcnt wait (immediate must be a literal)
template <int N>
__device__ __forceinline__ void waitvm() {
  if constexpr (N == 0) asm volatile("s_waitcnt vmcnt(0)" ::: "memory");
  else if constexpr (N == 4) asm volatile("s_waitcnt vmcnt(4)" ::: "memory");
  else static_assert(N == 0, "unsupported vmcnt literal");
}

// ---------------- fused prep: hs cvt + both weight transposes (one launch) ----------
__global__ __launch_bounds__(256) void prep_kernel(const float* __restrict__ hs,
                                                   unsigned short* __restrict__ hs_bf,
                                                   const float* __restrict__ w_attn,
                                                   unsigned short* __restrict__ wattnT,
                                                   const float* __restrict__ w_proj,
                                                   unsigned short* __restrict__ wprojT) {
  __shared__ unsigned short t[64][68];
  const int bx = blockIdx.x;
  const int tid = threadIdx.x;
  if (bx < 2048) {
    const int n8 = 8192 * 1024 / 8;
    int i = bx * 256 + tid;
    const int stride = 2048 * 256;
    for (; i < n8; i += stride) {
      float4 a = ((const float4*)hs)[2 * i];
      float4 b = ((const float4*)hs)[2 * i + 1];
      u16x8 o;
      o[0] = f2bf(a.x); o[1] = f2bf(a.y); o[2] = f2bf(a.z); o[3] = f2bf(a.w);
      o[4] = f2bf(b.x); o[5] = f2bf(b.y); o[6] = f2bf(b.z); o[7] = f2bf(b.w);
      ((u16x8*)hs_bf)[i] = o;
    }
    return;
  }
  const float* in;
  unsigned short* out;
  int R, C, c0, r0;
  if (bx < 2816) {
    int i = bx - 2048;
    in = w_attn; out = wattnT; R = 1024; C = 3072;
    c0 = (i % 48) * 64; r0 = (i / 48) * 64;
  } else {
    int i = bx - 2816;
    in = w_proj; out = wprojT; R = 1024; C = 1024;
    c0 = (i & 15) * 64; r0 = (i >> 4) * 64;
  }
#pragma unroll
  for (int i = 0; i < 4; ++i) {
    int idx = tid + i * 256;
    int rr = idx >> 4, cc4 = (idx & 15) * 4;
    float4 v = *(const float4*)(in + (size_t)(r0 + rr) * C + c0 + cc4);
    t[rr][cc4] = f2bf(v.x);
    t[rr][cc4 + 1] = f2bf(v.y);
    t[rr][cc4 + 2] = f2bf(v.z);
    t[rr][cc4 + 3] = f2bf(v.w);
  }
  __syncthreads();
#pragma unroll
  for (int i = 0; i < 2; ++i) {
    int idx = tid + i * 256;
    int row = idx >> 3, ch = (idx & 7) * 8;
    u16x8 o;
#pragma unroll
    for (int j = 0; j < 8; ++j) o[j] = t[ch + j][row];
    *(u16x8*)(out + (size_t)(c0 + row) * R + r0 + ch) = o;
  }
}

// XCD-bijective block swizzle (requires nwg % 8 == 0)
__device__ __forceinline__ void xcd_swizzle(int gx, int gy, int& bn, int& bm) {
  int orig = blockIdx.y * gx + blockIdx.x;
  int cpx = (gx * gy) >> 3;
  int swz = (orig & 7) * cpx + (orig >> 3);
  bn = swz % gx;
  bm = swz / gx;
}

// =========== 128M x 256N window-pipelined K-loop (BK=64, 16 tiles) ===========
__device__ __forceinline__ void kloop_128x256(const unsigned short* __restrict__ Ab,
                                              const unsigned short* __restrict__ Bb,
                                              char* smem, f32x4 (*acc)[4]) {
  const int tid = threadIdx.x;
  const int lane = tid & 63, wid = tid >> 6;
  const int g = lane >> 4, r = lane & 15;
  const int wr = wid >> 2, wc = wid & 3;

  int aoff[4][2], boff[4][2];
#pragma unroll
  for (int m4 = 0; m4 < 4; ++m4)
#pragma unroll
    for (int ks = 0; ks < 2; ++ks) {
      int row = wr * 64 + m4 * 16 + r;
      aoff[m4][ks] = row * 128 + ((ks * 64 + g * 16) ^ ((row & 7) << 4));
    }
#pragma unroll
  for (int ni = 0; ni < 4; ++ni)
#pragma unroll
    for (int ks = 0; ks < 2; ++ks) {
      int row = wc * 64 + ni * 16 + r;
      boff[ni][ks] = row * 128 + ((ks * 64 + g * 16) ^ ((row & 7) << 4));
    }

  const int sc = (((tid & 7) ^ ((tid >> 3) & 7)) << 4) >> 1;
  const int srow = tid >> 3;

  auto stageA = [&](int T) {
#pragma unroll
    for (int p = 0; p < 2; ++p)
      gload_lds16(Ab + (size_t)(p * 64 + srow) * 1024 + T * 64 + sc,
                  smem + (T & 1) * 16384 + (p * 512 + tid) * 16);
  };
  auto stageB = [&](int T, int hh) {
#pragma unroll
    for (int p = 0; p < 2; ++p)
      gload_lds16(Bb + (size_t)(hh * 128 + p * 64 + srow) * 1024 + T * 64 + sc,
                  smem + 32768 + (T & 1) * 32768 + hh * 16384 + (p * 512 + tid) * 16);
  };

  // prologue: tile 0
  stageA(0); stageB(0, 0); stageB(0, 1);

#pragma unroll 1
  for (int i = 0; i < 8; ++i) {
#pragma unroll
    for (int w = 0; w < 2; ++w) {
      const int T = 2 * i + w;
      const int abase = (T & 1) * 16384;
      const int bbase = 32768 + (T & 1) * 32768;
      const int fT = T + 1;
      waitvm<0>();
      __builtin_amdgcn_s_barrier();
      bf16x8 bfr[4];
#pragma unroll
      for (int ph = 0; ph < 4; ++ph) {
        const int ks = ph >> 1, mh = ph & 1;
        if (fT < 16) {
          if (ph == 0) stageA(fT);
          else if (ph == 1) stageB(fT, 0);
          else if (ph == 2) stageB(fT, 1);
        }
        if (mh == 0) {
#pragma unroll
          for (int ni = 0; ni < 4; ++ni)
            bfr[ni] = *(const bf16x8*)(smem + bbase + boff[ni][ks]);
        }
        bf16x8 afr[2];
#pragma unroll
        for (int m = 0; m < 2; ++m)
          afr[m] = *(const bf16x8*)(smem + abase + aoff[mh * 2 + m][ks]);
        asm volatile("s_waitcnt lgkmcnt(0)" ::: "memory");
        __builtin_amdgcn_sched_barrier(0);
        __builtin_amdgcn_s_setprio(1);
#pragma unroll
        for (int m = 0; m < 2; ++m)
#pragma unroll
          for (int ni = 0; ni < 4; ++ni)
            acc[mh * 2 + m][ni] =
                __builtin_amdgcn_mfma_f32_16x16x32_bf16(afr[m], bfr[ni], acc[mh * 2 + m][ni], 0, 0, 0);
        __builtin_amdgcn_s_setprio(0);
      }
    }
  }
}

// ---------------- GEMM1: qkv = hs @ W + b -> q/k [B,H,S,D] bf16, V transposed [B,H,D,S] --
// tile 128x256, grid 12x64 = 768 blocks = exactly 3 CU-waves. V-section (bn>=8) blocks
// bounce their tile through (now-dead) LDS and write V^T directly -> no transpose kernel.
__global__ __launch_bounds__(512, 2) void gemm_qkv(const unsigned short* __restrict__ A,
                                                   const unsigned short* __restrict__ Bt,
                                                   const float* __restrict__ bias,
                                                   unsigned short* __restrict__ qb,
                                                   unsigned short* __restrict__ kb,
                                                   unsigned short* __restrict__ vtb) {
  __shared__ __align__(16) char smem[98304];
  const int tid = threadIdx.x;
  const int lane = tid & 63, wid = tid >> 6;
  const int g = lane >> 4, r = lane & 15;
  const int wr = wid >> 2, wc = wid & 3;
  int bn, bm;
  xcd_swizzle(12, 64, bn, bm);
  f32x4 acc[4][4] = {};
  kloop_128x256(A + (size_t)(bm * 128) * 1024, Bt + (size_t)(bn * 256) * 1024, smem, acc);

  const int colbase = bn * 256 + wc * 64;
  const int rowbase = bm * 128 + wr * 64;
  const int sec = bn >> 2;
  const float QSCALE = 0.125f * 1.44269504f;
  if (sec < 2) {
#pragma unroll
    for (int m = 0; m < 4; ++m) {
#pragma unroll
      for (int n = 0; n < 4; ++n) {
#pragma unroll
        for (int reg = 0; reg < 4; ++reg) {
          int gm = rowbase + m * 16 + g * 4 + reg;
          int gn = colbase + n * 16 + r;
          float val = acc[m][n][reg] + bias[gn];
          int bb = gm >> 11, s = gm & 2047;
          int hc = gn & 1023;
          int h = hc >> 6, d = hc & 63;
          size_t oidx = (((size_t)(bb * 16 + h)) * 2048 + s) * 64 + d;
          if (sec == 0) qb[oidx] = f2bf(val * QSCALE);
          else kb[oidx] = f2bf(val);
        }
      }
    }
  } else {
    // V: transpose 128(s) x 256(hc) tile via LDS, write [B,H,D,S] coalesced
    unsigned short* t = (unsigned short*)smem;  // [256 cols][136 rows(+8 pad)]
    __syncthreads();  // all waves past their final lgkmcnt-fenced ds_reads
#pragma unroll
    for (int m = 0; m < 4; ++m) {
#pragma unroll
      for (int n = 0; n < 4; ++n) {
#pragma unroll
        for (int reg = 0; reg < 4; ++reg) {
          int row_l = wr * 64 + m * 16 + g * 4 + reg;   // s-local
          int col_l = wc * 64 + n * 16 + r;             // hc-local
          float val = acc[m][n][reg] + bias[2048 + (bn - 8) * 256 + col_l];
          t[col_l * 136 + row_l] = f2bf(val);
        }
      }
    }
    __syncthreads();
    const int bb = bm >> 4, srow0 = (bm & 15) * 128;
#pragma unroll
    for (int it = 0; it < 8; ++it) {
      int idx = tid + it * 512;
      int col_l = idx >> 4, s8 = idx & 15;
      u16x8 o;
#pragma unroll
      for (int j = 0; j < 8; ++j) o[j] = t[col_l * 136 + s8 * 8 + j];
      size_t didx = ((size_t)(bb * 1024 + (bn - 8) * 256 + col_l)) * 2048 + srow0 + s8 * 8;
      *(u16x8*)(vtb + didx) = o;
    }
  }
}

// ---------------- GEMM2: out = attn_out @ Wp + b (f32 out) ----------------
__global__ __launch_bounds__(512, 2) void gemm_proj(const unsigned short* __restrict__ A,
                                                    const unsigned short* __restrict__ Bt,
                                                    const float* __restrict__ bias,
                                                    float* __restrict__ out) {
  __shared__ __align__(16) char smem[98304];
  const int tid = threadIdx.x;
  const int lane = tid & 63, wid = tid >> 6;
  const int g = lane >> 4, r = lane & 15;
  const int wr = wid >> 2, wc = wid & 3;
  int bn, bm;
  xcd_swizzle(4, 64, bn, bm);
  f32x4 acc[4][4] = {};
  kloop_128x256(A + (size_t)(bm * 128) * 1024, Bt + (size_t)(bn * 256) * 1024, smem, acc);

  const int colbase = bn * 256 + wc * 64;
  const int rowbase = bm * 128 + wr * 64;
#pragma unroll
  for (int m = 0; m < 4; ++m) {
#pragma unroll
    for (int n = 0; n < 4; ++n) {
#pragma unroll
      for (int reg = 0; reg < 4; ++reg) {
        int gm = rowbase + m * 16 + g * 4 + reg;
        int gn = colbase + n * 16 + r;
        out[(size_t)gm * 1024 + gn] = acc[m][n][reg] + bias[gn];
      }
    }
  }
}

// ---------------- flash attention: 32x32 MFMA, in-register P, FIXED-MAX softmax --------
// (R14 4-wave version: q-tiles {bx,15-bx}, head-per-XCD, counted-vmcnt double-buffer)
__global__ __launch_bounds__(256) void attn_kernel(const unsigned short* __restrict__ qb,
                                                   const unsigned short* __restrict__ kb,
                                                   const unsigned short* __restrict__ vtb,
                                                   unsigned short* __restrict__ aout) {
  __shared__ char smem[32768];  // K dbuf 2x8KB @0 ; V dbuf 2x8KB @16384
  const int tid = threadIdx.x;
  const int wid = tid >> 6, lane = tid & 63;
  const int c = lane & 31, h = lane >> 5;
  const int o = blockIdx.y * 8 + blockIdx.x;
  const int bx = (o >> 3) & 7;
  const int bh = (o & 7) + ((o >> 6) << 3);
  const unsigned short* qbase = qb + (size_t)bh * 2048 * 64;
  const unsigned short* kbh = kb + (size_t)bh * 2048 * 64;
  const unsigned short* vbh = vtb + (size_t)bh * 64 * 2048;

  const int obA = wid * 2048 + lane * 16, obB = obA + 1024;
  const int rowA = obA >> 7, rowB = obB >> 7;
  const int ssA = ((obA >> 4) & 7) ^ (rowA & 7);
  const int ssB = ((obB >> 4) & 7) ^ (rowB & 7);
  const int kofA = rowA * 64 + ssA * 8, kofB = rowB * 64 + ssB * 8;
  const int vofA = rowA * 2048 + ssA * 8, vofB = rowB * 2048 + ssB * 8;
  const int dstA = wid * 2048, dstB = wid * 2048 + 1024;

  int off0[4], off1[4];
#pragma unroll
  for (int ks = 0; ks < 4; ++ks) {
    const int sl = ((2 * ks + h) ^ (c & 7)) << 4;
    off0[ks] = c * 128 + sl;
    off1[ks] = (32 + c) * 128 + sl;
  }

  auto mkpa = [&](const f32x16& P, bf16x8& paA, bf16x8& paB) {
    unsigned c0 = cvtpk(P[0], P[1]), c2 = cvtpk(P[2], P[3]);
    unsigned c4 = cvtpk(P[4], P[5]), c6 = cvtpk(P[6], P[7]);
    unsigned c8 = cvtpk(P[8], P[9]), c10 = cvtpk(P[10], P[11]);
    unsigned c12 = cvtpk(P[12], P[13]), c14 = cvtpk(P[14], P[15]);
    auto s0 = __builtin_amdgcn_permlane32_swap(c0, c4, false, false);
    auto s1 = __builtin_amdgcn_permlane32_swap(c2, c6, false, false);
    auto s2 = __builtin_amdgcn_permlane32_swap(c8, c12, false, false);
    auto s3 = __builtin_amdgcn_permlane32_swap(c10, c14, false, false);
    u32x4 wA = {s0[0], s1[0], s0[1], s1[1]};
    u32x4 wB = {s2[0], s3[0], s2[1], s3[1]};
    paA = __builtin_bit_cast(bf16x8, wA);
    paB = __builtin_bit_cast(bf16x8, wB);
  };

#pragma unroll 1
  for (int pi = 0; pi < 2; ++pi) {
    const int qt = (pi == 0) ? bx : (15 - bx);
    const int qrow0 = qt * 128 + wid * 32;
    const int qg = qrow0 + c;

    const unsigned short* kpA = kbh + kofA;
    const unsigned short* kpB = kbh + kofB;
    const unsigned short* vpA = vbh + vofA;
    const unsigned short* vpB = vbh + vofB;

    bf16x8 aq[4];
#pragma unroll
    for (int ks = 0; ks < 4; ++ks)
      aq[ks] = *(const bf16x8*)(qbase + (size_t)qg * 64 + ks * 16 + h * 8);

    f32x16 o0 = {}, o1 = {};
    float lrow = 0.f;

    const int nkv = (qt + 1) * 2;
    int cur = 0;
    gload_lds16(kpA, smem + dstA);
    gload_lds16(kpB, smem + dstB);
    gload_lds16(vpA, smem + 16384 + dstA);
    gload_lds16(vpB, smem + 16384 + dstB);
    kpA += 4096; kpB += 4096; vpA += 64; vpB += 64;

#pragma unroll 1
    for (int kt = 0; kt < nkv; ++kt) {
      const int kv0 = kt * 64;
      if (kt + 1 < nkv) {
        const int nb = (cur ^ 1) * 8192;
        gload_lds16(kpA, smem + nb + dstA);
        gload_lds16(kpB, smem + nb + dstB);
        gload_lds16(vpA, smem + 16384 + nb + dstA);
        gload_lds16(vpB, smem + 16384 + nb + dstB);
        kpA += 4096; kpB += 4096; vpA += 64; vpB += 64;
        waitvm<4>();
      } else {
        waitvm<0>();
      }
      __builtin_amdgcn_s_barrier();
      __builtin_amdgcn_sched_barrier(0);
      char* Kt = smem + cur * 8192;
      char* Vt = smem + 16384 + cur * 8192;

      f32x16 sw0 = {}, sw1 = {};
#pragma unroll
      for (int ks = 0; ks < 4; ++ks) {
        bf16x8 k0 = *(const bf16x8*)(Kt + off0[ks]);
        bf16x8 k1 = *(const bf16x8*)(Kt + off1[ks]);
        __builtin_amdgcn_s_setprio(1);
        sw0 = __builtin_amdgcn_mfma_f32_32x32x16_bf16(k0, aq[ks], sw0, 0, 0, 0);
        sw1 = __builtin_amdgcn_mfma_f32_32x32x16_bf16(k1, aq[ks], sw1, 0, 0, 0);
        __builtin_amdgcn_s_setprio(0);
      }

      if (kt >= 2 * qt) {
#pragma unroll
        for (int t = 0; t < 16; ++t) {
          int crow = (t & 3) + 8 * (t >> 2) + 4 * h;
          sw0[t] = (kv0 + crow > qg) ? -1e30f : sw0[t];
          sw1[t] = (kv0 + 32 + crow > qg) ? -1e30f : sw1[t];
        }
      }

      // fixed-max: P = exp2(s) directly; row-sum tree + one shfl
      float s_[16];
#pragma unroll
      for (int t = 0; t < 16; ++t) {
        sw0[t] = __builtin_amdgcn_exp2f(sw0[t]);
        sw1[t] = __builtin_amdgcn_exp2f(sw1[t]);
        s_[t] = sw0[t] + sw1[t];
      }
#pragma unroll
      for (int s = 8; s > 0; s >>= 1)
#pragma unroll
        for (int t = 0; t < 8; ++t)
          if (t < s) s_[t] += s_[t + s];
      lrow += s_[0] + __shfl_xor(s_[0], 32);

      bf16x8 pa[4];
      mkpa(sw0, pa[0], pa[1]);
      mkpa(sw1, pa[2], pa[3]);

#pragma unroll
      for (int kst = 0; kst < 4; ++kst) {
        bf16x8 v0 = *(const bf16x8*)(Vt + off0[kst]);
        bf16x8 v1 = *(const bf16x8*)(Vt + off1[kst]);
        __builtin_amdgcn_s_setprio(1);
        o0 = __builtin_amdgcn_mfma_f32_32x32x16_bf16(pa[kst], v0, o0, 0, 0, 0);
        o1 = __builtin_amdgcn_mfma_f32_32x32x16_bf16(pa[kst], v1, o1, 0, 0, 0);
        __builtin_amdgcn_s_setprio(0);
      }
      __builtin_amdgcn_s_barrier();
      cur ^= 1;
    }

    const int b_ = bh >> 4, hh = bh & 15;
    float linv = 1.f / lrow;
    float invt[16];
#pragma unroll
    for (int t = 0; t < 16; ++t)
      invt[t] = __shfl(linv, (t & 3) + 8 * (t >> 2) + 4 * h);
#pragma unroll
    for (int t = 0; t < 16; ++t) {
      int rowg = b_ * 2048 + qrow0 + (t & 3) + 8 * (t >> 2) + 4 * h;
      unsigned short* rp = aout + (size_t)rowg * 1024 + hh * 64;
      rp[c] = f2bf(o0[t] * invt[t]);
      rp[32 + c] = f2bf(o1[t] * invt[t]);
    }
  }
}

extern "C" void kernel_launch(void* const* d_in, const int* in_sizes, int n_in,
                              void* d_out, int out_size, void* d_ws, size_t ws_size,
                              hipStream_t stream) {
  const float* hs = (const float*)d_in[0];      // [4,2048,1024]
  const float* w_attn = (const float*)d_in[1];  // [1024,3072]
  const float* b_attn = (const float*)d_in[2];  // [3072]
  const float* w_proj = (const float*)d_in[3];  // [1024,1024]
  const float* b_proj = (const float*)d_in[4];  // [1024]
  float* out = (float*)d_out;                   // [4,2048,1024] f32
  char* ws = (char*)d_ws;
  size_t off = 0;
  auto alloc = [&](size_t sz) {
    char* p = ws + off;
    off = (off + sz + 255) & ~(size_t)255;
    return p;
  };
  unsigned short* hs_bf = (unsigned short*)alloc((size_t)8192 * 1024 * 2);
  unsigned short* wattnT = (unsigned short*)alloc((size_t)3072 * 1024 * 2);
  unsigned short* wprojT = (unsigned short*)alloc((size_t)1024 * 1024 * 2);
  unsigned short* qbuf = (unsigned short*)alloc((size_t)8192 * 1024 * 2);
  unsigned short* kbuf = (unsigned short*)alloc((size_t)8192 * 1024 * 2);
  unsigned short* vtb = (unsigned short*)alloc((size_t)8192 * 1024 * 2);
  unsigned short* aout = hs_bf;  // hs_bf dead after gemm_qkv; reuse

  prep_kernel<<<3072, 256, 0, stream>>>(hs, hs_bf, w_attn, wattnT, w_proj, wprojT);
  gemm_qkv<<<dim3(12, 64), 512, 0, stream>>>(hs_bf, wattnT, b_attn, qbuf, kbuf, vtb);
  attn_kernel<<<dim3(8, 64), 256, 0, stream>>>(qbuf, kbuf, vtb, aout);
  gemm_proj<<<dim3(4, 64), 512, 0, stream>>>(aout, wprojT, b_proj, out);
}

// Round 17
// 146.365 us; speedup vs baseline: 1.1089x; 1.0364x over previous
//
#include <hip/hip_runtime.h>
#include <stdint.h>

typedef short bf16x8 __attribute__((ext_vector_type(8)));
typedef unsigned short u16x8 __attribute__((ext_vector_type(8)));
typedef float f32x4 __attribute__((ext_vector_type(4)));
typedef float f32x16 __attribute__((ext_vector_type(16)));
typedef unsigned int u32x4 __attribute__((ext_vector_type(4)));

__device__ __forceinline__ unsigned short f2bf(float f) {
  unsigned int u = __builtin_bit_cast(unsigned int, f);
  u += 0x7fffu + ((u >> 16) & 1u);
  return (unsigned short)(u >> 16);
}

__device__ __forceinline__ unsigned int cvtpk(float a, float b) {
  unsigned int r;
  asm("v_cvt_pk_bf16_f32 %0, %1, %2" : "=v"(r) : "v"(a), "v"(b));
  return r;
}

__device__ __forceinline__ void gload_lds16(const void* g, void* l) {
  __builtin_amdgcn_global_load_lds(
      (const __attribute__((address_space(1))) unsigned int*)g,
      (__attribute__((address_space(3))) unsigned int*)l, 16, 0, 0);
}

// counted vmcnt wait (immediate must be a literal)
template <int N>
__device__ __forceinline__ void waitvm() {
  if constexpr (N == 0) asm volatile("s_waitcnt vmcnt(0)" ::: "memory");
  else if constexpr (N == 4) asm volatile("s_waitcnt vmcnt(4)" ::: "memory");
  else static_assert(N == 0, "unsupported vmcnt literal");
}

// ---------------- fused prep: hs cvt + both weight transposes (one launch) ----------
__global__ __launch_bounds__(256) void prep_kernel(const float* __restrict__ hs,
                                                   unsigned short* __restrict__ hs_bf,
                                                   const float* __restrict__ w_attn,
                                                   unsigned short* __restrict__ wattnT,
                                                   const float* __restrict__ w_proj,
                                                   unsigned short* __restrict__ wprojT) {
  __shared__ unsigned short t[64][68];
  const int bx = blockIdx.x;
  const int tid = threadIdx.x;
  if (bx < 2048) {
    const int n8 = 8192 * 1024 / 8;
    int i = bx * 256 + tid;
    const int stride = 2048 * 256;
    for (; i < n8; i += stride) {
      float4 a = ((const float4*)hs)[2 * i];
      float4 b = ((const float4*)hs)[2 * i + 1];
      u16x8 o;
      o[0] = f2bf(a.x); o[1] = f2bf(a.y); o[2] = f2bf(a.z); o[3] = f2bf(a.w);
      o[4] = f2bf(b.x); o[5] = f2bf(b.y); o[6] = f2bf(b.z); o[7] = f2bf(b.w);
      ((u16x8*)hs_bf)[i] = o;
    }
    return;
  }
  const float* in;
  unsigned short* out;
  int R, C, c0, r0;
  if (bx < 2816) {
    int i = bx - 2048;
    in = w_attn; out = wattnT; R = 1024; C = 3072;
    c0 = (i % 48) * 64; r0 = (i / 48) * 64;
  } else {
    int i = bx - 2816;
    in = w_proj; out = wprojT; R = 1024; C = 1024;
    c0 = (i & 15) * 64; r0 = (i >> 4) * 64;
  }
#pragma unroll
  for (int i = 0; i < 4; ++i) {
    int idx = tid + i * 256;
    int rr = idx >> 4, cc4 = (idx & 15) * 4;
    float4 v = *(const float4*)(in + (size_t)(r0 + rr) * C + c0 + cc4);
    t[rr][cc4] = f2bf(v.x);
    t[rr][cc4 + 1] = f2bf(v.y);
    t[rr][cc4 + 2] = f2bf(v.z);
    t[rr][cc4 + 3] = f2bf(v.w);
  }
  __syncthreads();
#pragma unroll
  for (int i = 0; i < 2; ++i) {
    int idx = tid + i * 256;
    int row = idx >> 3, ch = (idx & 7) * 8;
    u16x8 o;
#pragma unroll
    for (int j = 0; j < 8; ++j) o[j] = t[ch + j][row];
    *(u16x8*)(out + (size_t)(c0 + row) * R + r0 + ch) = o;
  }
}

// XCD-bijective block swizzle (requires nwg % 8 == 0)
__device__ __forceinline__ void xcd_swizzle(int gx, int gy, int& bn, int& bm) {
  int orig = blockIdx.y * gx + blockIdx.x;
  int cpx = (gx * gy) >> 3;
  int swz = (orig & 7) * cpx + (orig >> 3);
  bn = swz % gx;
  bm = swz / gx;
}

// =========== 128M x 256N window-pipelined K-loop (BK=64, 16 tiles) ===========
__device__ __forceinline__ void kloop_128x256(const unsigned short* __restrict__ Ab,
                                              const unsigned short* __restrict__ Bb,
                                              char* smem, f32x4 (*acc)[4]) {
  const int tid = threadIdx.x;
  const int lane = tid & 63, wid = tid >> 6;
  const int g = lane >> 4, r = lane & 15;
  const int wr = wid >> 2, wc = wid & 3;

  int aoff[4][2], boff[4][2];
#pragma unroll
  for (int m4 = 0; m4 < 4; ++m4)
#pragma unroll
    for (int ks = 0; ks < 2; ++ks) {
      int row = wr * 64 + m4 * 16 + r;
      aoff[m4][ks] = row * 128 + ((ks * 64 + g * 16) ^ ((row & 7) << 4));
    }
#pragma unroll
  for (int ni = 0; ni < 4; ++ni)
#pragma unroll
    for (int ks = 0; ks < 2; ++ks) {
      int row = wc * 64 + ni * 16 + r;
      boff[ni][ks] = row * 128 + ((ks * 64 + g * 16) ^ ((row & 7) << 4));
    }

  const int sc = (((tid & 7) ^ ((tid >> 3) & 7)) << 4) >> 1;
  const int srow = tid >> 3;

  auto stageA = [&](int T) {
#pragma unroll
    for (int p = 0; p < 2; ++p)
      gload_lds16(Ab + (size_t)(p * 64 + srow) * 1024 + T * 64 + sc,
                  smem + (T & 1) * 16384 + (p * 512 + tid) * 16);
  };
  auto stageB = [&](int T, int hh) {
#pragma unroll
    for (int p = 0; p < 2; ++p)
      gload_lds16(Bb + (size_t)(hh * 128 + p * 64 + srow) * 1024 + T * 64 + sc,
                  smem + 32768 + (T & 1) * 32768 + hh * 16384 + (p * 512 + tid) * 16);
  };

  // prologue: tile 0
  stageA(0); stageB(0, 0); stageB(0, 1);

#pragma unroll 1
  for (int i = 0; i < 8; ++i) {
#pragma unroll
    for (int w = 0; w < 2; ++w) {
      const int T = 2 * i + w;
      const int abase = (T & 1) * 16384;
      const int bbase = 32768 + (T & 1) * 32768;
      const int fT = T + 1;
      waitvm<0>();
      __builtin_amdgcn_s_barrier();
      bf16x8 bfr[4];
#pragma unroll
      for (int ph = 0; ph < 4; ++ph) {
        const int ks = ph >> 1, mh = ph & 1;
        if (fT < 16) {
          if (ph == 0) stageA(fT);
          else if (ph == 1) stageB(fT, 0);
          else if (ph == 2) stageB(fT, 1);
        }
        if (mh == 0) {
#pragma unroll
          for (int ni = 0; ni < 4; ++ni)
            bfr[ni] = *(const bf16x8*)(smem + bbase + boff[ni][ks]);
        }
        bf16x8 afr[2];
#pragma unroll
        for (int m = 0; m < 2; ++m)
          afr[m] = *(const bf16x8*)(smem + abase + aoff[mh * 2 + m][ks]);
        asm volatile("s_waitcnt lgkmcnt(0)" ::: "memory");
        __builtin_amdgcn_sched_barrier(0);
        __builtin_amdgcn_s_setprio(1);
#pragma unroll
        for (int m = 0; m < 2; ++m)
#pragma unroll
          for (int ni = 0; ni < 4; ++ni)
            acc[mh * 2 + m][ni] =
                __builtin_amdgcn_mfma_f32_16x16x32_bf16(afr[m], bfr[ni], acc[mh * 2 + m][ni], 0, 0, 0);
        __builtin_amdgcn_s_setprio(0);
      }
    }
  }
}

// ---------------- GEMM1: qkv = hs @ W + b -> q/k [B,H,S,D] bf16, V transposed [B,H,D,S] --
__global__ __launch_bounds__(512, 2) void gemm_qkv(const unsigned short* __restrict__ A,
                                                   const unsigned short* __restrict__ Bt,
                                                   const float* __restrict__ bias,
                                                   unsigned short* __restrict__ qb,
                                                   unsigned short* __restrict__ kb,
                                                   unsigned short* __restrict__ vtb) {
  __shared__ __align__(16) char smem[98304];
  const int tid = threadIdx.x;
  const int lane = tid & 63, wid = tid >> 6;
  const int g = lane >> 4, r = lane & 15;
  const int wr = wid >> 2, wc = wid & 3;
  int bn, bm;
  xcd_swizzle(12, 64, bn, bm);
  f32x4 acc[4][4] = {};
  kloop_128x256(A + (size_t)(bm * 128) * 1024, Bt + (size_t)(bn * 256) * 1024, smem, acc);

  const int colbase = bn * 256 + wc * 64;
  const int rowbase = bm * 128 + wr * 64;
  const int sec = bn >> 2;
  const float QSCALE = 0.125f * 1.44269504f;
  if (sec < 2) {
#pragma unroll
    for (int m = 0; m < 4; ++m) {
#pragma unroll
      for (int n = 0; n < 4; ++n) {
#pragma unroll
        for (int reg = 0; reg < 4; ++reg) {
          int gm = rowbase + m * 16 + g * 4 + reg;
          int gn = colbase + n * 16 + r;
          float val = acc[m][n][reg] + bias[gn];
          int bb = gm >> 11, s = gm & 2047;
          int hc = gn & 1023;
          int h = hc >> 6, d = hc & 63;
          size_t oidx = (((size_t)(bb * 16 + h)) * 2048 + s) * 64 + d;
          if (sec == 0) qb[oidx] = f2bf(val * QSCALE);
          else kb[oidx] = f2bf(val);
        }
      }
    }
  } else {
    // V: transpose 128(s) x 256(hc) tile via LDS, write [B,H,D,S] coalesced
    unsigned short* t = (unsigned short*)smem;  // [256 cols][136 rows(+8 pad)]
    __syncthreads();
#pragma unroll
    for (int m = 0; m < 4; ++m) {
#pragma unroll
      for (int n = 0; n < 4; ++n) {
#pragma unroll
        for (int reg = 0; reg < 4; ++reg) {
          int row_l = wr * 64 + m * 16 + g * 4 + reg;
          int col_l = wc * 64 + n * 16 + r;
          float val = acc[m][n][reg] + bias[2048 + (bn - 8) * 256 + col_l];
          t[col_l * 136 + row_l] = f2bf(val);
        }
      }
    }
    __syncthreads();
    const int bb = bm >> 4, srow0 = (bm & 15) * 128;
#pragma unroll
    for (int it = 0; it < 8; ++it) {
      int idx = tid + it * 512;
      int col_l = idx >> 4, s8 = idx & 15;
      u16x8 o;
#pragma unroll
      for (int j = 0; j < 8; ++j) o[j] = t[col_l * 136 + s8 * 8 + j];
      size_t didx = ((size_t)(bb * 1024 + (bn - 8) * 256 + col_l)) * 2048 + srow0 + s8 * 8;
      *(u16x8*)(vtb + didx) = o;
    }
  }
}

// ---------------- GEMM2: out = attn_out @ Wp + b (f32 out) ----------------
__global__ __launch_bounds__(512, 2) void gemm_proj(const unsigned short* __restrict__ A,
                                                    const unsigned short* __restrict__ Bt,
                                                    const float* __restrict__ bias,
                                                    float* __restrict__ out) {
  __shared__ __align__(16) char smem[98304];
  const int tid = threadIdx.x;
  const int lane = tid & 63, wid = tid >> 6;
  const int g = lane >> 4, r = lane & 15;
  const int wr = wid >> 2, wc = wid & 3;
  int bn, bm;
  xcd_swizzle(4, 64, bn, bm);
  f32x4 acc[4][4] = {};
  kloop_128x256(A + (size_t)(bm * 128) * 1024, Bt + (size_t)(bn * 256) * 1024, smem, acc);

  const int colbase = bn * 256 + wc * 64;
  const int rowbase = bm * 128 + wr * 64;
#pragma unroll
  for (int m = 0; m < 4; ++m) {
#pragma unroll
    for (int n = 0; n < 4; ++n) {
#pragma unroll
      for (int reg = 0; reg < 4; ++reg) {
        int gm = rowbase + m * 16 + g * 4 + reg;
        int gn = colbase + n * 16 + r;
        out[(size_t)gm * 1024 + gn] = acc[m][n][reg] + bias[gn];
      }
    }
  }
}

// ---------------- flash attention: split-KV wave specialization ----------
// q [B,H,S,D] (pre-scaled by 0.125*log2e), k [B,H,S,D], vt [B,H,D,S] -> aout [B*S,E] bf16
// 4 waves (qw x kw): wave owns 32 q-rows (qw half of 64-row chunk) x kv-half kw of each
// 64-kv tile. Fixed-max softmax is tile-linear -> kw-pair merge is a pure add through
// LDS at chunk end. Block o (grid 1024): bh=(o&7)+8*(o>>7); p=(o>>3)&15; chunks {p,31-p}
// -> 33 tiles/block uniform. 4 blocks/CU = 4 streams/SIMD (was 2).
__global__ __launch_bounds__(256, 4) void attn_kernel(const unsigned short* __restrict__ qb,
                                                      const unsigned short* __restrict__ kb,
                                                      const unsigned short* __restrict__ vtb,
                                                      unsigned short* __restrict__ aout) {
  __shared__ char smem[32768];  // K dbuf 2x8KB @0 ; V dbuf 2x8KB @16384 ; merge reuses @0
  const int tid = threadIdx.x;
  const int wid = tid >> 6, lane = tid & 63;
  const int c = lane & 31, h = lane >> 5;
  const int qw = wid >> 1, kw = wid & 1;
  const int o = blockIdx.x;
  const int p = (o >> 3) & 15;
  const int bh = (o & 7) + 8 * (o >> 7);
  const unsigned short* qbase = qb + (size_t)bh * 2048 * 64;
  const unsigned short* kbh = kb + (size_t)bh * 2048 * 64;
  const unsigned short* vbh = vtb + (size_t)bh * 64 * 2048;

  // staging geometry (tile-invariant, 4 gload/thread per tile)
  const int obA = wid * 2048 + lane * 16, obB = obA + 1024;
  const int rowA = obA >> 7, rowB = obB >> 7;
  const int ssA = ((obA >> 4) & 7) ^ (rowA & 7);
  const int ssB = ((obB >> 4) & 7) ^ (rowB & 7);
  const int kofA = rowA * 64 + ssA * 8, kofB = rowB * 64 + ssB * 8;
  const int vofA = rowA * 2048 + ssA * 8, vofB = rowB * 2048 + ssB * 8;
  const int dstA = wid * 2048, dstB = wid * 2048 + 1024;

  // LDS read offsets: K rows kw*32+c (full d via ks=0..3); V rows c / 32+c, kv-half kw
  int koff[4], voff0[2], voff1[2];
#pragma unroll
  for (int ks = 0; ks < 4; ++ks)
    koff[ks] = (kw * 32 + c) * 128 + (((2 * ks + h) ^ (c & 7)) << 4);
#pragma unroll
  for (int ks = 0; ks < 2; ++ks) {
    const int sl = ((2 * ks + h + 4 * kw) ^ (c & 7)) << 4;
    voff0[ks] = c * 128 + sl;
    voff1[ks] = (32 + c) * 128 + sl;
  }

  auto mkpa = [&](const f32x16& P, bf16x8& paA, bf16x8& paB) {
    unsigned c0 = cvtpk(P[0], P[1]), c2 = cvtpk(P[2], P[3]);
    unsigned c4 = cvtpk(P[4], P[5]), c6 = cvtpk(P[6], P[7]);
    unsigned c8 = cvtpk(P[8], P[9]), c10 = cvtpk(P[10], P[11]);
    unsigned c12 = cvtpk(P[12], P[13]), c14 = cvtpk(P[14], P[15]);
    auto s0 = __builtin_amdgcn_permlane32_swap(c0, c4, false, false);
    auto s1 = __builtin_amdgcn_permlane32_swap(c2, c6, false, false);
    auto s2 = __builtin_amdgcn_permlane32_swap(c8, c12, false, false);
    auto s3 = __builtin_amdgcn_permlane32_swap(c10, c14, false, false);
    u32x4 wA = {s0[0], s1[0], s0[1], s1[1]};
    u32x4 wB = {s2[0], s3[0], s2[1], s3[1]};
    paA = __builtin_bit_cast(bf16x8, wA);
    paB = __builtin_bit_cast(bf16x8, wB);
  };

#pragma unroll 1
  for (int pi = 0; pi < 2; ++pi) {
    const int chunk = (pi == 0) ? p : (31 - p);
    const int qrow0 = chunk * 64 + qw * 32;
    const int qg = qrow0 + c;  // this lane's q-row

    const unsigned short* kpA = kbh + kofA;
    const unsigned short* kpB = kbh + kofB;
    const unsigned short* vpA = vbh + vofA;
    const unsigned short* vpB = vbh + vofB;

    bf16x8 aq[4];
#pragma unroll
    for (int ks = 0; ks < 4; ++ks)
      aq[ks] = *(const bf16x8*)(qbase + (size_t)qg * 64 + ks * 16 + h * 8);

    f32x16 o0 = {}, o1 = {};
    float lrow = 0.f;

    const int nkv = chunk + 1;
    int cur = 0;
    gload_lds16(kpA, smem + dstA);
    gload_lds16(kpB, smem + dstB);
    gload_lds16(vpA, smem + 16384 + dstA);
    gload_lds16(vpB, smem + 16384 + dstB);
    kpA += 4096; kpB += 4096; vpA += 64; vpB += 64;

#pragma unroll 1
    for (int kt = 0; kt < nkv; ++kt) {
      if (kt + 1 < nkv) {
        const int nb = (cur ^ 1) * 8192;
        gload_lds16(kpA, smem + nb + dstA);
        gload_lds16(kpB, smem + nb + dstB);
        gload_lds16(vpA, smem + 16384 + nb + dstA);
        gload_lds16(vpB, smem + 16384 + nb + dstB);
        kpA += 4096; kpB += 4096; vpA += 64; vpB += 64;
        waitvm<4>();
      } else {
        waitvm<0>();
      }
      __builtin_amdgcn_s_barrier();
      __builtin_amdgcn_sched_barrier(0);
      char* Kt = smem + cur * 8192;
      char* Vt = smem + 16384 + cur * 8192;

      // QK^T swapped, this wave's kv-half: sw = mfma32x32(K_half, Q) -> D[kv][q]
      f32x16 sw = {};
#pragma unroll
      for (int ks = 0; ks < 4; ++ks) {
        bf16x8 kf = *(const bf16x8*)(Kt + koff[ks]);
        __builtin_amdgcn_s_setprio(1);
        sw = __builtin_amdgcn_mfma_f32_32x32x16_bf16(kf, aq[ks], sw, 0, 0, 0);
        __builtin_amdgcn_s_setprio(0);
      }

      // causal mask on the diagonal tile
      if (kt == nkv - 1) {
        const int kv0h = kt * 64 + kw * 32;
#pragma unroll
        for (int t = 0; t < 16; ++t) {
          int crow = (t & 3) + 8 * (t >> 2) + 4 * h;
          sw[t] = (kv0h + crow > qg) ? -1e30f : sw[t];
        }
      }

      // fixed-max: P = exp2(s); partial row-sum (this kv-half)
      float s_[8];
#pragma unroll
      for (int t = 0; t < 16; ++t) sw[t] = __builtin_amdgcn_exp2f(sw[t]);
#pragma unroll
      for (int t = 0; t < 8; ++t) s_[t] = sw[t] + sw[t + 8];
#pragma unroll
      for (int s = 4; s > 0; s >>= 1)
#pragma unroll
        for (int t = 0; t < 4; ++t)
          if (t < s) s_[t] += s_[t + s];
      lrow += s_[0] + __shfl_xor(s_[0], 32);

      // P -> bf16 A-frags in-register
      bf16x8 pa0, pa1;
      mkpa(sw, pa0, pa1);

      // PV over this kv-half: 4 MFMA
      bf16x8 v00 = *(const bf16x8*)(Vt + voff0[0]);
      bf16x8 v01 = *(const bf16x8*)(Vt + voff0[1]);
      bf16x8 v10 = *(const bf16x8*)(Vt + voff1[0]);
      bf16x8 v11 = *(const bf16x8*)(Vt + voff1[1]);
      __builtin_amdgcn_s_setprio(1);
      o0 = __builtin_amdgcn_mfma_f32_32x32x16_bf16(pa0, v00, o0, 0, 0, 0);
      o0 = __builtin_amdgcn_mfma_f32_32x32x16_bf16(pa1, v01, o0, 0, 0, 0);
      o1 = __builtin_amdgcn_mfma_f32_32x32x16_bf16(pa0, v10, o1, 0, 0, 0);
      o1 = __builtin_amdgcn_mfma_f32_32x32x16_bf16(pa1, v11, o1, 0, 0, 0);
      __builtin_amdgcn_s_setprio(0);
      __builtin_amdgcn_s_barrier();  // all waves done reading buf[cur]
      cur ^= 1;
    }

    // ---- kw-pair merge (pure add; fixed-max is tile-linear). K/V LDS is dead. ----
    if (kw) {
#pragma unroll
      for (int j = 0; j < 4; ++j) {
        f32x4 v0 = {o0[4 * j], o0[4 * j + 1], o0[4 * j + 2], o0[4 * j + 3]};
        f32x4 v1 = {o1[4 * j], o1[4 * j + 1], o1[4 * j + 2], o1[4 * j + 3]};
        *(f32x4*)(smem + qw * 8192 + j * 1024 + lane * 16) = v0;
        *(f32x4*)(smem + qw * 8192 + (4 + j) * 1024 + lane * 16) = v1;
      }
      *(float*)(smem + 16384 + qw * 256 + lane * 4) = lrow;
    }
    __syncthreads();
    if (!kw) {
#pragma unroll
      for (int j = 0; j < 4; ++j) {
        f32x4 v0 = *(const f32x4*)(smem + qw * 8192 + j * 1024 + lane * 16);
        f32x4 v1 = *(const f32x4*)(smem + qw * 8192 + (4 + j) * 1024 + lane * 16);
#pragma unroll
        for (int k = 0; k < 4; ++k) {
          o0[4 * j + k] += v0[k];
          o1[4 * j + k] += v1[k];
        }
      }
      lrow += *(const float*)(smem + 16384 + qw * 256 + lane * 4);

      const int b_ = bh >> 4, hh = bh & 15;
      float linv = 1.f / lrow;
      float invt[16];
#pragma unroll
      for (int t = 0; t < 16; ++t)
        invt[t] = __shfl(linv, (t & 3) + 8 * (t >> 2) + 4 * h);
#pragma unroll
      for (int t = 0; t < 16; ++t) {
        int rowg = b_ * 2048 + qrow0 + (t & 3) + 8 * (t >> 2) + 4 * h;
        unsigned short* rp = aout + (size_t)rowg * 1024 + hh * 64;
        rp[c] = f2bf(o0[t] * invt[t]);
        rp[32 + c] = f2bf(o1[t] * invt[t]);
      }
    }
    __syncthreads();  // merge reads done before next chunk's staging overwrites
  }
}

extern "C" void kernel_launch(void* const* d_in, const int* in_sizes, int n_in,
                              void* d_out, int out_size, void* d_ws, size_t ws_size,
                              hipStream_t stream) {
  const float* hs = (const float*)d_in[0];      // [4,2048,1024]
  const float* w_attn = (const float*)d_in[1];  // [1024,3072]
  const float* b_attn = (const float*)d_in[2];  // [3072]
  const float* w_proj = (const float*)d_in[3];  // [1024,1024]
  const float* b_proj = (const float*)d_in[4];  // [1024]
  float* out = (float*)d_out;                   // [4,2048,1024] f32
  char* ws = (char*)d_ws;
  size_t off = 0;
  auto alloc = [&](size_t sz) {
    char* p = ws + off;
    off = (off + sz + 255) & ~(size_t)255;
    return p;
  };
  unsigned short* hs_bf = (unsigned short*)alloc((size_t)8192 * 1024 * 2);
  unsigned short* wattnT = (unsigned short*)alloc((size_t)3072 * 1024 * 2);
  unsigned short* wprojT = (unsigned short*)alloc((size_t)1024 * 1024 * 2);
  unsigned short* qbuf = (unsigned short*)alloc((size_t)8192 * 1024 * 2);
  unsigned short* kbuf = (unsigned short*)alloc((size_t)8192 * 1024 * 2);
  unsigned short* vtb = (unsigned short*)alloc((size_t)8192 * 1024 * 2);
  unsigned short* aout = hs_bf;  // hs_bf dead after gemm_qkv; reuse

  prep_kernel<<<3072, 256, 0, stream>>>(hs, hs_bf, w_attn, wattnT, w_proj, wprojT);
  gemm_qkv<<<dim3(12, 64), 512, 0, stream>>>(hs_bf, wattnT, b_attn, qbuf, kbuf, vtb);
  attn_kernel<<<1024, 256, 0, stream>>>(qbuf, kbuf, vtb, aout);
  gemm_proj<<<dim3(4, 64), 512, 0, stream>>>(aout, wprojT, b_proj, out);
}

// Round 18
// 144.593 us; speedup vs baseline: 1.1225x; 1.0123x over previous
//
#include <hip/hip_runtime.h>
#include <stdint.h>

typedef short bf16x8 __attribute__((ext_vector_type(8)));
typedef unsigned short u16x8 __attribute__((ext_vector_type(8)));
typedef float f32x4 __attribute__((ext_vector_type(4)));
typedef float f32x16 __attribute__((ext_vector_type(16)));
typedef unsigned int u32x4 __attribute__((ext_vector_type(4)));

__device__ __forceinline__ unsigned short f2bf(float f) {
  unsigned int u = __builtin_bit_cast(unsigned int, f);
  u += 0x7fffu + ((u >> 16) & 1u);
  return (unsigned short)(u >> 16);
}

__device__ __forceinline__ unsigned int cvtpk(float a, float b) {
  unsigned int r;
  asm("v_cvt_pk_bf16_f32 %0, %1, %2" : "=v"(r) : "v"(a), "v"(b));
  return r;
}

__device__ __forceinline__ void gload_lds16(const void* g, void* l) {
  __builtin_amdgcn_global_load_lds(
      (const __attribute__((address_space(1))) unsigned int*)g,
      (__attribute__((address_space(3))) unsigned int*)l, 16, 0, 0);
}

// counted vmcnt wait (immediate must be a literal)
template <int N>
__device__ __forceinline__ void waitvm() {
  if constexpr (N == 0) asm volatile("s_waitcnt vmcnt(0)" ::: "memory");
  else if constexpr (N == 4) asm volatile("s_waitcnt vmcnt(4)" ::: "memory");
  else static_assert(N == 0, "unsupported vmcnt literal");
}

// ---------------- fused prep: hs cvt + both weight transposes (one launch) ----------
__global__ __launch_bounds__(256) void prep_kernel(const float* __restrict__ hs,
                                                   unsigned short* __restrict__ hs_bf,
                                                   const float* __restrict__ w_attn,
                                                   unsigned short* __restrict__ wattnT,
                                                   const float* __restrict__ w_proj,
                                                   unsigned short* __restrict__ wprojT) {
  __shared__ unsigned short t[64][68];
  const int bx = blockIdx.x;
  const int tid = threadIdx.x;
  if (bx < 2048) {
    const int n8 = 8192 * 1024 / 8;
    int i = bx * 256 + tid;
    const int stride = 2048 * 256;
    for (; i < n8; i += stride) {
      float4 a = ((const float4*)hs)[2 * i];
      float4 b = ((const float4*)hs)[2 * i + 1];
      u16x8 o;
      o[0] = f2bf(a.x); o[1] = f2bf(a.y); o[2] = f2bf(a.z); o[3] = f2bf(a.w);
      o[4] = f2bf(b.x); o[5] = f2bf(b.y); o[6] = f2bf(b.z); o[7] = f2bf(b.w);
      ((u16x8*)hs_bf)[i] = o;
    }
    return;
  }
  const float* in;
  unsigned short* out;
  int R, C, c0, r0;
  if (bx < 2816) {
    int i = bx - 2048;
    in = w_attn; out = wattnT; R = 1024; C = 3072;
    c0 = (i % 48) * 64; r0 = (i / 48) * 64;
  } else {
    int i = bx - 2816;
    in = w_proj; out = wprojT; R = 1024; C = 1024;
    c0 = (i & 15) * 64; r0 = (i >> 4) * 64;
  }
#pragma unroll
  for (int i = 0; i < 4; ++i) {
    int idx = tid + i * 256;
    int rr = idx >> 4, cc4 = (idx & 15) * 4;
    float4 v = *(const float4*)(in + (size_t)(r0 + rr) * C + c0 + cc4);
    t[rr][cc4] = f2bf(v.x);
    t[rr][cc4 + 1] = f2bf(v.y);
    t[rr][cc4 + 2] = f2bf(v.z);
    t[rr][cc4 + 3] = f2bf(v.w);
  }
  __syncthreads();
#pragma unroll
  for (int i = 0; i < 2; ++i) {
    int idx = tid + i * 256;
    int row = idx >> 3, ch = (idx & 7) * 8;
    u16x8 o;
#pragma unroll
    for (int j = 0; j < 8; ++j) o[j] = t[ch + j][row];
    *(u16x8*)(out + (size_t)(c0 + row) * R + r0 + ch) = o;
  }
}

// XCD-bijective block swizzle (requires nwg % 8 == 0)
__device__ __forceinline__ void xcd_swizzle(int gx, int gy, int& bn, int& bm) {
  int orig = blockIdx.y * gx + blockIdx.x;
  int cpx = (gx * gy) >> 3;
  int swz = (orig & 7) * cpx + (orig >> 3);
  bn = swz % gx;
  bm = swz / gx;
}

// =========== 128M x 256N window-pipelined K-loop (BK=64, 16 tiles) ===========
__device__ __forceinline__ void kloop_128x256(const unsigned short* __restrict__ Ab,
                                              const unsigned short* __restrict__ Bb,
                                              char* smem, f32x4 (*acc)[4]) {
  const int tid = threadIdx.x;
  const int lane = tid & 63, wid = tid >> 6;
  const int g = lane >> 4, r = lane & 15;
  const int wr = wid >> 2, wc = wid & 3;

  int aoff[4][2], boff[4][2];
#pragma unroll
  for (int m4 = 0; m4 < 4; ++m4)
#pragma unroll
    for (int ks = 0; ks < 2; ++ks) {
      int row = wr * 64 + m4 * 16 + r;
      aoff[m4][ks] = row * 128 + ((ks * 64 + g * 16) ^ ((row & 7) << 4));
    }
#pragma unroll
  for (int ni = 0; ni < 4; ++ni)
#pragma unroll
    for (int ks = 0; ks < 2; ++ks) {
      int row = wc * 64 + ni * 16 + r;
      boff[ni][ks] = row * 128 + ((ks * 64 + g * 16) ^ ((row & 7) << 4));
    }

  const int sc = (((tid & 7) ^ ((tid >> 3) & 7)) << 4) >> 1;
  const int srow = tid >> 3;

  auto stageA = [&](int T) {
#pragma unroll
    for (int p = 0; p < 2; ++p)
      gload_lds16(Ab + (size_t)(p * 64 + srow) * 1024 + T * 64 + sc,
                  smem + (T & 1) * 16384 + (p * 512 + tid) * 16);
  };
  auto stageB = [&](int T, int hh) {
#pragma unroll
    for (int p = 0; p < 2; ++p)
      gload_lds16(Bb + (size_t)(hh * 128 + p * 64 + srow) * 1024 + T * 64 + sc,
                  smem + 32768 + (T & 1) * 32768 + hh * 16384 + (p * 512 + tid) * 16);
  };

  // prologue: tile 0
  stageA(0); stageB(0, 0); stageB(0, 1);

#pragma unroll 1
  for (int i = 0; i < 8; ++i) {
#pragma unroll
    for (int w = 0; w < 2; ++w) {
      const int T = 2 * i + w;
      const int abase = (T & 1) * 16384;
      const int bbase = 32768 + (T & 1) * 32768;
      const int fT = T + 1;
      waitvm<0>();
      __builtin_amdgcn_s_barrier();
      bf16x8 bfr[4];
#pragma unroll
      for (int ph = 0; ph < 4; ++ph) {
        const int ks = ph >> 1, mh = ph & 1;
        if (fT < 16) {
          if (ph == 0) stageA(fT);
          else if (ph == 1) stageB(fT, 0);
          else if (ph == 2) stageB(fT, 1);
        }
        if (mh == 0) {
#pragma unroll
          for (int ni = 0; ni < 4; ++ni)
            bfr[ni] = *(const bf16x8*)(smem + bbase + boff[ni][ks]);
        }
        bf16x8 afr[2];
#pragma unroll
        for (int m = 0; m < 2; ++m)
          afr[m] = *(const bf16x8*)(smem + abase + aoff[mh * 2 + m][ks]);
        asm volatile("s_waitcnt lgkmcnt(0)" ::: "memory");
        __builtin_amdgcn_sched_barrier(0);
        __builtin_amdgcn_s_setprio(1);
#pragma unroll
        for (int m = 0; m < 2; ++m)
#pragma unroll
          for (int ni = 0; ni < 4; ++ni)
            acc[mh * 2 + m][ni] =
                __builtin_amdgcn_mfma_f32_16x16x32_bf16(afr[m], bfr[ni], acc[mh * 2 + m][ni], 0, 0, 0);
        __builtin_amdgcn_s_setprio(0);
      }
    }
  }
}

// ---------------- GEMM1: qkv = hs @ W + b -> q/k [B,H,S,D] bf16, V transposed [B,H,D,S] --
__global__ __launch_bounds__(512, 2) void gemm_qkv(const unsigned short* __restrict__ A,
                                                   const unsigned short* __restrict__ Bt,
                                                   const float* __restrict__ bias,
                                                   unsigned short* __restrict__ qb,
                                                   unsigned short* __restrict__ kb,
                                                   unsigned short* __restrict__ vtb) {
  __shared__ __align__(16) char smem[98304];
  const int tid = threadIdx.x;
  const int lane = tid & 63, wid = tid >> 6;
  const int g = lane >> 4, r = lane & 15;
  const int wr = wid >> 2, wc = wid & 3;
  int bn, bm;
  xcd_swizzle(12, 64, bn, bm);
  f32x4 acc[4][4] = {};
  kloop_128x256(A + (size_t)(bm * 128) * 1024, Bt + (size_t)(bn * 256) * 1024, smem, acc);

  const int colbase = bn * 256 + wc * 64;
  const int rowbase = bm * 128 + wr * 64;
  const int sec = bn >> 2;
  const float QSCALE = 0.125f * 1.44269504f;
  if (sec < 2) {
#pragma unroll
    for (int m = 0; m < 4; ++m) {
#pragma unroll
      for (int n = 0; n < 4; ++n) {
#pragma unroll
        for (int reg = 0; reg < 4; ++reg) {
          int gm = rowbase + m * 16 + g * 4 + reg;
          int gn = colbase + n * 16 + r;
          float val = acc[m][n][reg] + bias[gn];
          int bb = gm >> 11, s = gm & 2047;
          int hc = gn & 1023;
          int h = hc >> 6, d = hc & 63;
          size_t oidx = (((size_t)(bb * 16 + h)) * 2048 + s) * 64 + d;
          if (sec == 0) qb[oidx] = f2bf(val * QSCALE);
          else kb[oidx] = f2bf(val);
        }
      }
    }
  } else {
    // V: transpose 128(s) x 256(hc) tile via LDS, write [B,H,D,S] coalesced
    unsigned short* t = (unsigned short*)smem;  // [256 cols][136 rows(+8 pad)]
    __syncthreads();
#pragma unroll
    for (int m = 0; m < 4; ++m) {
#pragma unroll
      for (int n = 0; n < 4; ++n) {
#pragma unroll
        for (int reg = 0; reg < 4; ++reg) {
          int row_l = wr * 64 + m * 16 + g * 4 + reg;
          int col_l = wc * 64 + n * 16 + r;
          float val = acc[m][n][reg] + bias[2048 + (bn - 8) * 256 + col_l];
          t[col_l * 136 + row_l] = f2bf(val);
        }
      }
    }
    __syncthreads();
    const int bb = bm >> 4, srow0 = (bm & 15) * 128;
#pragma unroll
    for (int it = 0; it < 8; ++it) {
      int idx = tid + it * 512;
      int col_l = idx >> 4, s8 = idx & 15;
      u16x8 o;
#pragma unroll
      for (int j = 0; j < 8; ++j) o[j] = t[col_l * 136 + s8 * 8 + j];
      size_t didx = ((size_t)(bb * 1024 + (bn - 8) * 256 + col_l)) * 2048 + srow0 + s8 * 8;
      *(u16x8*)(vtb + didx) = o;
    }
  }
}

// ---------------- GEMM2: out = attn_out @ Wp + b (f32 out) ----------------
__global__ __launch_bounds__(512, 2) void gemm_proj(const unsigned short* __restrict__ A,
                                                    const unsigned short* __restrict__ Bt,
                                                    const float* __restrict__ bias,
                                                    float* __restrict__ out) {
  __shared__ __align__(16) char smem[98304];
  const int tid = threadIdx.x;
  const int lane = tid & 63, wid = tid >> 6;
  const int g = lane >> 4, r = lane & 15;
  const int wr = wid >> 2, wc = wid & 3;
  int bn, bm;
  xcd_swizzle(4, 64, bn, bm);
  f32x4 acc[4][4] = {};
  kloop_128x256(A + (size_t)(bm * 128) * 1024, Bt + (size_t)(bn * 256) * 1024, smem, acc);

  const int colbase = bn * 256 + wc * 64;
  const int rowbase = bm * 128 + wr * 64;
#pragma unroll
  for (int m = 0; m < 4; ++m) {
#pragma unroll
    for (int n = 0; n < 4; ++n) {
#pragma unroll
      for (int reg = 0; reg < 4; ++reg) {
        int gm = rowbase + m * 16 + g * 4 + reg;
        int gn = colbase + n * 16 + r;
        out[(size_t)gm * 1024 + gn] = acc[m][n][reg] + bias[gn];
      }
    }
  }
}

// ---------------- flash attention: split-KV, wide bank mask, 1 barrier/tile ----------
// q [B,H,S,D] (pre-scaled by 0.125*log2e), k [B,H,S,D], vt [B,H,D,S] -> aout [B*S,E] bf16
// Bank mask m(row) = (row&7)^((row>>3)&7) applied BOTH at staging (pre-swizzled global
// source) and reads -> lanes whose rows differ by 8/16/24 land on distinct bank groups.
// One barrier per tile: waitvm(0) [own tile-kt loads] -> s_barrier [tile staged block-
// wide AND all kt-1 readers done] -> stage(kt+1 into buf^1) [WAR-safe] -> compute.
__global__ __launch_bounds__(256, 4) void attn_kernel(const unsigned short* __restrict__ qb,
                                                      const unsigned short* __restrict__ kb,
                                                      const unsigned short* __restrict__ vtb,
                                                      unsigned short* __restrict__ aout) {
  __shared__ char smem[32768];  // K dbuf 2x8KB @0 ; V dbuf 2x8KB @16384 ; merge reuses @0
  const int tid = threadIdx.x;
  const int wid = tid >> 6, lane = tid & 63;
  const int c = lane & 31, h = lane >> 5;
  const int qw = wid >> 1, kw = wid & 1;
  const int o = blockIdx.x;
  const int p = (o >> 3) & 15;
  const int bh = (o & 7) + 8 * (o >> 7);
  const unsigned short* qbase = qb + (size_t)bh * 2048 * 64;
  const unsigned short* kbh = kb + (size_t)bh * 2048 * 64;
  const unsigned short* vbh = vtb + (size_t)bh * 64 * 2048;

  // staging geometry (tile-invariant, 4 gload/thread per tile); wide mask
  const int obA = wid * 2048 + lane * 16, obB = obA + 1024;
  const int rowA = obA >> 7, rowB = obB >> 7;
  const int mA = (rowA & 7) ^ ((rowA >> 3) & 7);
  const int mB = (rowB & 7) ^ ((rowB >> 3) & 7);
  const int ssA = ((obA >> 4) & 7) ^ mA;
  const int ssB = ((obB >> 4) & 7) ^ mB;
  const int kofA = rowA * 64 + ssA * 8, kofB = rowB * 64 + ssB * 8;
  const int vofA = rowA * 2048 + ssA * 8, vofB = rowB * 2048 + ssB * 8;
  const int dstA = wid * 2048, dstB = wid * 2048 + 1024;

  // LDS read offsets with matching wide mask
  int koff[4], voff0[2], voff1[2];
  {
    const int krow = kw * 32 + c;
    const int mk = (krow & 7) ^ ((krow >> 3) & 7);
#pragma unroll
    for (int ks = 0; ks < 4; ++ks)
      koff[ks] = krow * 128 + (((2 * ks + h) ^ mk) << 4);
    const int m0 = (c & 7) ^ ((c >> 3) & 7);
    const int m1 = (c & 7) ^ ((4 + (c >> 3)) & 7);
#pragma unroll
    for (int ks = 0; ks < 2; ++ks) {
      voff0[ks] = c * 128 + (((2 * ks + h + 4 * kw) ^ m0) << 4);
      voff1[ks] = (32 + c) * 128 + (((2 * ks + h + 4 * kw) ^ m1) << 4);
    }
  }

  auto mkpa = [&](const f32x16& P, bf16x8& paA, bf16x8& paB) {
    unsigned c0 = cvtpk(P[0], P[1]), c2 = cvtpk(P[2], P[3]);
    unsigned c4 = cvtpk(P[4], P[5]), c6 = cvtpk(P[6], P[7]);
    unsigned c8 = cvtpk(P[8], P[9]), c10 = cvtpk(P[10], P[11]);
    unsigned c12 = cvtpk(P[12], P[13]), c14 = cvtpk(P[14], P[15]);
    auto s0 = __builtin_amdgcn_permlane32_swap(c0, c4, false, false);
    auto s1 = __builtin_amdgcn_permlane32_swap(c2, c6, false, false);
    auto s2 = __builtin_amdgcn_permlane32_swap(c8, c12, false, false);
    auto s3 = __builtin_amdgcn_permlane32_swap(c10, c14, false, false);
    u32x4 wA = {s0[0], s1[0], s0[1], s1[1]};
    u32x4 wB = {s2[0], s3[0], s2[1], s3[1]};
    paA = __builtin_bit_cast(bf16x8, wA);
    paB = __builtin_bit_cast(bf16x8, wB);
  };

#pragma unroll 1
  for (int pi = 0; pi < 2; ++pi) {
    const int chunk = (pi == 0) ? p : (31 - p);
    const int qrow0 = chunk * 64 + qw * 32;
    const int qg = qrow0 + c;  // this lane's q-row

    const unsigned short* kpA = kbh + kofA;
    const unsigned short* kpB = kbh + kofB;
    const unsigned short* vpA = vbh + vofA;
    const unsigned short* vpB = vbh + vofB;

    bf16x8 aq[4];
#pragma unroll
    for (int ks = 0; ks < 4; ++ks)
      aq[ks] = *(const bf16x8*)(qbase + (size_t)qg * 64 + ks * 16 + h * 8);

    f32x16 o0 = {}, o1 = {};
    float lrow = 0.f;

    const int nkv = chunk + 1;
    int cur = 0;
    // prologue: stage tile 0 into buf 0
    gload_lds16(kpA, smem + dstA);
    gload_lds16(kpB, smem + dstB);
    gload_lds16(vpA, smem + 16384 + dstA);
    gload_lds16(vpB, smem + 16384 + dstB);
    kpA += 4096; kpB += 4096; vpA += 64; vpB += 64;

#pragma unroll 1
    for (int kt = 0; kt < nkv; ++kt) {
      waitvm<0>();                       // own tile-kt loads landed
      __builtin_amdgcn_s_barrier();      // staged block-wide; kt-1 readers done
      __builtin_amdgcn_sched_barrier(0);
      if (kt + 1 < nkv) {                // WAR-safe: after barrier
        const int nb = (cur ^ 1) * 8192;
        gload_lds16(kpA, smem + nb + dstA);
        gload_lds16(kpB, smem + nb + dstB);
        gload_lds16(vpA, smem + 16384 + nb + dstA);
        gload_lds16(vpB, smem + 16384 + nb + dstB);
        kpA += 4096; kpB += 4096; vpA += 64; vpB += 64;
      }
      char* Kt = smem + cur * 8192;
      char* Vt = smem + 16384 + cur * 8192;

      // QK^T swapped, this wave's kv-half: sw = mfma32x32(K_half, Q) -> D[kv][q]
      f32x16 sw = {};
#pragma unroll
      for (int ks = 0; ks < 4; ++ks) {
        bf16x8 kf = *(const bf16x8*)(Kt + koff[ks]);
        __builtin_amdgcn_s_setprio(1);
        sw = __builtin_amdgcn_mfma_f32_32x32x16_bf16(kf, aq[ks], sw, 0, 0, 0);
        __builtin_amdgcn_s_setprio(0);
      }

      // causal mask on the diagonal tile
      if (kt == nkv - 1) {
        const int kv0h = kt * 64 + kw * 32;
#pragma unroll
        for (int t = 0; t < 16; ++t) {
          int crow = (t & 3) + 8 * (t >> 2) + 4 * h;
          sw[t] = (kv0h + crow > qg) ? -1e30f : sw[t];
        }
      }

      // fixed-max: P = exp2(s); partial row-sum (this kv-half)
      float s_[8];
#pragma unroll
      for (int t = 0; t < 16; ++t) sw[t] = __builtin_amdgcn_exp2f(sw[t]);
#pragma unroll
      for (int t = 0; t < 8; ++t) s_[t] = sw[t] + sw[t + 8];
#pragma unroll
      for (int s = 4; s > 0; s >>= 1)
#pragma unroll
        for (int t = 0; t < 4; ++t)
          if (t < s) s_[t] += s_[t + s];
      lrow += s_[0] + __shfl_xor(s_[0], 32);

      // P -> bf16 A-frags in-register
      bf16x8 pa0, pa1;
      mkpa(sw, pa0, pa1);

      // PV over this kv-half: 4 MFMA
      bf16x8 v00 = *(const bf16x8*)(Vt + voff0[0]);
      bf16x8 v01 = *(const bf16x8*)(Vt + voff0[1]);
      bf16x8 v10 = *(const bf16x8*)(Vt + voff1[0]);
      bf16x8 v11 = *(const bf16x8*)(Vt + voff1[1]);
      __builtin_amdgcn_s_setprio(1);
      o0 = __builtin_amdgcn_mfma_f32_32x32x16_bf16(pa0, v00, o0, 0, 0, 0);
      o0 = __builtin_amdgcn_mfma_f32_32x32x16_bf16(pa1, v01, o0, 0, 0, 0);
      o1 = __builtin_amdgcn_mfma_f32_32x32x16_bf16(pa0, v10, o1, 0, 0, 0);
      o1 = __builtin_amdgcn_mfma_f32_32x32x16_bf16(pa1, v11, o1, 0, 0, 0);
      __builtin_amdgcn_s_setprio(0);
      cur ^= 1;
    }
    __builtin_amdgcn_s_barrier();  // all PV reads done before merge writes into smem

    // ---- kw-pair merge (pure add; fixed-max is tile-linear). K/V LDS is dead. ----
    if (kw) {
#pragma unroll
      for (int j = 0; j < 4; ++j) {
        f32x4 v0 = {o0[4 * j], o0[4 * j + 1], o0[4 * j + 2], o0[4 * j + 3]};
        f32x4 v1 = {o1[4 * j], o1[4 * j + 1], o1[4 * j + 2], o1[4 * j + 3]};
        *(f32x4*)(smem + qw * 8192 + j * 1024 + lane * 16) = v0;
        *(f32x4*)(smem + qw * 8192 + (4 + j) * 1024 + lane * 16) = v1;
      }
      *(float*)(smem + 16384 + qw * 256 + lane * 4) = lrow;
    }
    __syncthreads();
    if (!kw) {
#pragma unroll
      for (int j = 0; j < 4; ++j) {
        f32x4 v0 = *(const f32x4*)(smem + qw * 8192 + j * 1024 + lane * 16);
        f32x4 v1 = *(const f32x4*)(smem + qw * 8192 + (4 + j) * 1024 + lane * 16);
#pragma unroll
        for (int k = 0; k < 4; ++k) {
          o0[4 * j + k] += v0[k];
          o1[4 * j + k] += v1[k];
        }
      }
      lrow += *(const float*)(smem + 16384 + qw * 256 + lane * 4);

      const int b_ = bh >> 4, hh = bh & 15;
      float linv = 1.f / lrow;
      float invt[16];
#pragma unroll
      for (int t = 0; t < 16; ++t)
        invt[t] = __shfl(linv, (t & 3) + 8 * (t >> 2) + 4 * h);
#pragma unroll
      for (int t = 0; t < 16; ++t) {
        int rowg = b_ * 2048 + qrow0 + (t & 3) + 8 * (t >> 2) + 4 * h;
        unsigned short* rp = aout + (size_t)rowg * 1024 + hh * 64;
        rp[c] = f2bf(o0[t] * invt[t]);
        rp[32 + c] = f2bf(o1[t] * invt[t]);
      }
    }
    __syncthreads();  // merge reads done before next chunk's staging overwrites
  }
}

extern "C" void kernel_launch(void* const* d_in, const int* in_sizes, int n_in,
                              void* d_out, int out_size, void* d_ws, size_t ws_size,
                              hipStream_t stream) {
  const float* hs = (const float*)d_in[0];      // [4,2048,1024]
  const float* w_attn = (const float*)d_in[1];  // [1024,3072]
  const float* b_attn = (const float*)d_in[2];  // [3072]
  const float* w_proj = (const float*)d_in[3];  // [1024,1024]
  const float* b_proj = (const float*)d_in[4];  // [1024]
  float* out = (float*)d_out;                   // [4,2048,1024] f32
  char* ws = (char*)d_ws;
  size_t off = 0;
  auto alloc = [&](size_t sz) {
    char* p = ws + off;
    off = (off + sz + 255) & ~(size_t)255;
    return p;
  };
  unsigned short* hs_bf = (unsigned short*)alloc((size_t)8192 * 1024 * 2);
  unsigned short* wattnT = (unsigned short*)alloc((size_t)3072 * 1024 * 2);
  unsigned short* wprojT = (unsigned short*)alloc((size_t)1024 * 1024 * 2);
  unsigned short* qbuf = (unsigned short*)alloc((size_t)8192 * 1024 * 2);
  unsigned short* kbuf = (unsigned short*)alloc((size_t)8192 * 1024 * 2);
  unsigned short* vtb = (unsigned short*)alloc((size_t)8192 * 1024 * 2);
  unsigned short* aout = hs_bf;  // hs_bf dead after gemm_qkv; reuse

  prep_kernel<<<3072, 256, 0, stream>>>(hs, hs_bf, w_attn, wattnT, w_proj, wprojT);
  gemm_qkv<<<dim3(12, 64), 512, 0, stream>>>(hs_bf, wattnT, b_attn, qbuf, kbuf, vtb);
  attn_kernel<<<1024, 256, 0, stream>>>(qbuf, kbuf, vtb, aout);
  gemm_proj<<<dim3(4, 64), 512, 0, stream>>>(aout, wprojT, b_proj, out);
}